// Round 14
// baseline (309.763 us; speedup 1.0000x reference)
//
#include <hip/hip_runtime.h>

// VGAE encoder: 3x GCNConv (improved=True), N=100000, E=1600000.
//   xb = bf16(x); ax = Agg(xb); hw = relu(ax@W1+b1)@[Wm|Ws] (MFMA); z = Agg(hw)+[bm|bs]
// R14 == R13 intent (nt hints for read-once/write-once streams) with the
// compile fix: __builtin_nontemporal_* requires native vector types, so all
// HIP_vector_type accesses go through ext_vector_type shims.

#define DIM 128
#define LAT 32
#define CHUNK 4096        // edges per histogram/scatter block
#define BSH 8             // bucket shift: bucket = dst>>8 (256 nodes/bucket)

typedef short bf16x8 __attribute__((ext_vector_type(8)));
typedef float f32x4 __attribute__((ext_vector_type(4)));
typedef float f32x4v __attribute__((ext_vector_type(4)));
typedef int   i32x2v __attribute__((ext_vector_type(2)));
typedef unsigned u32x4v __attribute__((ext_vector_type(4)));

__device__ __forceinline__ unsigned short f2bf(float f) {   // RNE
    unsigned u = __float_as_uint(f);
    return (unsigned short)((u + 0x7fffu + ((u >> 16) & 1u)) >> 16);
}
__device__ __forceinline__ unsigned packbf(float a, float b) {
    return (unsigned)f2bf(a) | ((unsigned)f2bf(b) << 16);
}
__device__ __forceinline__ float2 bfp2f(unsigned u) {
    float2 r;
    r.x = __uint_as_float(u << 16);
    r.y = __uint_as_float(u & 0xffff0000u);
    return r;
}
// ---- nontemporal shims (native-vector types only) ----
__device__ __forceinline__ int2 nt_ld_i2(const int2* p) {
    i32x2v v = __builtin_nontemporal_load(reinterpret_cast<const i32x2v*>(p));
    return make_int2(v[0], v[1]);
}
__device__ __forceinline__ float4 nt_ld_f4(const float4* p) {
    f32x4v v = __builtin_nontemporal_load(reinterpret_cast<const f32x4v*>(p));
    float4 r; r.x = v[0]; r.y = v[1]; r.z = v[2]; r.w = v[3]; return r;
}
__device__ __forceinline__ void nt_st_f4(float4* p, float4 v) {
    f32x4v o = {v.x, v.y, v.z, v.w};
    __builtin_nontemporal_store(o, reinterpret_cast<f32x4v*>(p));
}
__device__ __forceinline__ void nt_st_u4(uint4* p, uint4 v) {
    u32x4v o = {v.x, v.y, v.z, v.w};
    __builtin_nontemporal_store(o, reinterpret_cast<u32x4v*>(p));
}

// FUSED: blocks [0,NCH): per-chunk bucket histogram -> gh[bin*NCH+chunk];
// [NCH,NCH+XB): x f32->bf16; rest: weight transpose+cast.
__global__ __launch_bounds__(256) void k_hist(const int* __restrict__ dst, int E,
                                              int* __restrict__ gh, int NCH, int NBK,
                                              const float* __restrict__ x,
                                              uint4* __restrict__ xb,
                                              const float* __restrict__ W1,
                                              const float* __restrict__ Wm,
                                              const float* __restrict__ Ws,
                                              unsigned short* __restrict__ w1t,
                                              unsigned short* __restrict__ wct,
                                              int XB) {
    const int c = blockIdx.x;
    if (c < NCH) {
        __shared__ int h[512];
        for (int b = threadIdx.x; b < NBK; b += 256) h[b] = 0;
        __syncthreads();
        int end = min(E, (c + 1) * CHUNK);
        for (int e = c * CHUNK + threadIdx.x; e < end; e += 256)
            atomicAdd(&h[dst[e] >> BSH], 1);
        __syncthreads();
        for (int b = threadIdx.x; b < NBK; b += 256) gh[b * NCH + c] = h[b];
    } else if (c < NCH + XB) {
        size_t i = ((size_t)(c - NCH) * 256 + threadIdx.x) * 16;
        const float4* xin = reinterpret_cast<const float4*>(x + i);
        float4 v0 = nt_ld_f4(xin);
        float4 v1 = nt_ld_f4(xin + 1);
        float4 v2 = nt_ld_f4(xin + 2);
        float4 v3 = nt_ld_f4(xin + 3);
        uint4 o0, o1;
        o0.x = packbf(v0.x, v0.y); o0.y = packbf(v0.z, v0.w);
        o0.z = packbf(v1.x, v1.y); o0.w = packbf(v1.z, v1.w);
        o1.x = packbf(v2.x, v2.y); o1.y = packbf(v2.z, v2.w);
        o1.z = packbf(v3.x, v3.y); o1.w = packbf(v3.z, v3.w);
        xb[i / 8] = o0;
        xb[i / 8 + 1] = o1;
    } else {
        int i = (c - NCH - XB) * 256 + threadIdx.x;
        if (i < DIM * DIM) {
            int cc = i >> 7, k = i & 127;
            w1t[cc * DIM + k] = f2bf(W1[k * DIM + cc]);
        }
        i -= DIM * DIM;
        if (i >= 0 && i < 64 * DIM) {
            int cc = i >> 7, k = i & 127;
            wct[cc * DIM + k] = f2bf((cc < LAT) ? Wm[k * LAT + cc] : Ws[k * LAT + (cc - LAT)]);
        }
    }
}

// per-bucket total: btot[b] = sum over chunks of gh[b][*]
__global__ __launch_bounds__(256) void k_btot(const int* __restrict__ gh, int NCH,
                                              int* __restrict__ btot) {
    __shared__ int sdata[256];
    const int b = blockIdx.x;
    int sum = 0;
    for (int t = threadIdx.x; t < NCH; t += 256) sum += gh[b * NCH + t];
    sdata[threadIdx.x] = sum;
    __syncthreads();
    for (int off = 128; off > 0; off >>= 1) {
        if (threadIdx.x < off) sdata[threadIdx.x] += sdata[threadIdx.x + off];
        __syncthreads();
    }
    if (threadIdx.x == 0) btot[b] = sdata[0];
}

// per-bucket row scan: gh[b][c] -> bbase[b] + exclusive prefix (global positions).
__global__ __launch_bounds__(256) void k_rowscan(int* __restrict__ gh, int NCH, int NBK,
                                                 const int* __restrict__ btot,
                                                 int* __restrict__ bbase, int E) {
    __shared__ int sdata[256];
    __shared__ int basepfx;
    const int b = blockIdx.x;
    const int t = threadIdx.x;
    if (t == 0) {
        int s = 0;
        for (int j = 0; j < b; ++j) s += btot[j];
        basepfx = s;
        bbase[b] = s;
        if (b == NBK - 1) bbase[NBK] = s + btot[b];
    }
    __syncthreads();
    int i0 = 2 * t, i1 = 2 * t + 1;
    int v0 = (i0 < NCH) ? gh[b * NCH + i0] : 0;
    int v1 = (i1 < NCH) ? gh[b * NCH + i1] : 0;
    int tot = v0 + v1;
    sdata[t] = tot;
    __syncthreads();
    for (int off = 1; off < 256; off <<= 1) {
        int xv = 0;
        if (t >= off) xv = sdata[t - off];
        __syncthreads();
        if (t >= off) sdata[t] += xv;
        __syncthreads();
    }
    int pfx = basepfx + sdata[t] - tot;   // exclusive across pairs
    if (i0 < NCH) gh[b * NCH + i0] = pfx;
    if (i1 < NCH) gh[b * NCH + i1] = pfx + v0;
}

// scatter edges into bucket-ordered bkt[]: LDS cursors, NO global atomics.
// record = {src | (dst&255)<<17, ew bits}
__global__ __launch_bounds__(256) void k_bucket(const int* __restrict__ src,
                                                const int* __restrict__ dst,
                                                const float* __restrict__ ew,
                                                const int* __restrict__ gh, int NCH, int NBK,
                                                int2* __restrict__ bkt, int E) {
    __shared__ int cur[512];
    const int c = blockIdx.x;
    for (int b = threadIdx.x; b < NBK; b += 256) cur[b] = gh[b * NCH + c];
    __syncthreads();
    int end = min(E, (c + 1) * CHUNK);
    for (int e = c * CHUNK + threadIdx.x; e < end; e += 256) {
        int d = __builtin_nontemporal_load(dst + e);
        int s = __builtin_nontemporal_load(src + e);
        float wv = __builtin_nontemporal_load(ew + e);
        int b = d >> BSH;
        int p = atomicAdd(&cur[b], 1);    // LDS atomic: fast
        bkt[p] = make_int2(s | ((d & 255) << 17), __float_as_int(wv));
    }
}

// per-bucket exact placement: rowptr + csr + deg/dinv, all LDS-local.
__global__ __launch_bounds__(256) void k_build(const int2* __restrict__ bkt,
                                               const int* __restrict__ bbase,
                                               int* __restrict__ rowptr,
                                               int2* __restrict__ csr,
                                               float* __restrict__ dinv, int N, int E) {
    __shared__ int cnt[256];
    __shared__ int offs[256];
    __shared__ int cnt2[256];
    __shared__ float degf[256];
    __shared__ int sdata[256];
    const int b = blockIdx.x;
    const int t = threadIdx.x;
    const int start = bbase[b], endb = bbase[b + 1];
    cnt[t] = 0; cnt2[t] = 0; degf[t] = 0.f;
    __syncthreads();
    for (int idx = start + t; idx < endb; idx += 256) {
        int2 rec = nt_ld_i2(bkt + idx);
        int dl = (rec.x >> 17) & 255;
        atomicAdd(&cnt[dl], 1);
        atomicAdd(&degf[dl], __int_as_float(rec.y));
    }
    __syncthreads();
    int myc = cnt[t];
    sdata[t] = myc;
    __syncthreads();
    for (int off = 1; off < 256; off <<= 1) {
        int xv = 0;
        if (t >= off) xv = sdata[t - off];
        __syncthreads();
        if (t >= off) sdata[t] += xv;
        __syncthreads();
    }
    offs[t] = sdata[t] - myc;             // exclusive
    int node = (b << BSH) + t;
    if (node < N) {
        rowptr[node] = start + offs[t];
        float deg = 2.0f + degf[t];       // improved=True self-loop weight
        dinv[node] = (deg > 0.0f) ? rsqrtf(deg) : 0.0f;
    }
    if (b == 0 && t == 0) rowptr[N] = E;
    __syncthreads();
    for (int idx = start + t; idx < endb; idx += 256) {
        int2 rec = nt_ld_i2(bkt + idx);
        int dl = (rec.x >> 17) & 255;
        int r = atomicAdd(&cnt2[dl], 1);
        csr[start + offs[dl] + r] = make_int2(rec.x & 0x1FFFF, rec.y);
    }
}

// wave per node; quarter q handles edges p0+q, p0+q+4,...; 16 lanes x uint4 = 256B row;
// unroll-4 per quarter; shfl_xor(16/32) combine; quarter 0 writes (nt).
// csr nt-loaded (read-once); xb kept L2-resident.
__global__ __launch_bounds__(256) void k_gather128(const int2* __restrict__ csr,
                                                   const int* __restrict__ rowptr,
                                                   const float* __restrict__ dinv,
                                                   const uint4* __restrict__ xb,
                                                   uint4* __restrict__ axb, int N) {
    int node = (blockIdx.x * 256 + threadIdx.x) >> 6;
    int lane = threadIdx.x & 63;
    if (node >= N) return;
    const int q = lane >> 4;
    const int l = lane & 15;
    float di = dinv[node];
    float acc[8];
#pragma unroll
    for (int j = 0; j < 8; ++j) acc[j] = 0.f;
    if (q == 0) {                  // self-loop once
        uint4 sv = xb[(size_t)node * 16 + l];
        float sl = 2.0f * di;
        float2 s0 = bfp2f(sv.x), s1 = bfp2f(sv.y), s2 = bfp2f(sv.z), s3 = bfp2f(sv.w);
        acc[0] = s0.x * sl; acc[1] = s0.y * sl;
        acc[2] = s1.x * sl; acc[3] = s1.y * sl;
        acc[4] = s2.x * sl; acc[5] = s2.y * sl;
        acc[6] = s3.x * sl; acc[7] = s3.y * sl;
    }
    int p = rowptr[node] + q;
    int end = rowptr[node + 1];
    for (; p + 12 < end; p += 16) {
        int2 e0 = nt_ld_i2(csr + p);
        int2 e1 = nt_ld_i2(csr + p + 4);
        int2 e2 = nt_ld_i2(csr + p + 8);
        int2 e3 = nt_ld_i2(csr + p + 12);
        float n0 = __int_as_float(e0.y) * dinv[e0.x];
        float n1 = __int_as_float(e1.y) * dinv[e1.x];
        float n2 = __int_as_float(e2.y) * dinv[e2.x];
        float n3 = __int_as_float(e3.y) * dinv[e3.x];
        uint4 u0 = xb[(size_t)e0.x * 16 + l];
        uint4 u1 = xb[(size_t)e1.x * 16 + l];
        uint4 u2 = xb[(size_t)e2.x * 16 + l];
        uint4 u3 = xb[(size_t)e3.x * 16 + l];
        {
            float2 a0 = bfp2f(u0.x), a1 = bfp2f(u0.y), a2 = bfp2f(u0.z), a3 = bfp2f(u0.w);
            acc[0] = fmaf(a0.x, n0, acc[0]); acc[1] = fmaf(a0.y, n0, acc[1]);
            acc[2] = fmaf(a1.x, n0, acc[2]); acc[3] = fmaf(a1.y, n0, acc[3]);
            acc[4] = fmaf(a2.x, n0, acc[4]); acc[5] = fmaf(a2.y, n0, acc[5]);
            acc[6] = fmaf(a3.x, n0, acc[6]); acc[7] = fmaf(a3.y, n0, acc[7]);
        }
        {
            float2 a0 = bfp2f(u1.x), a1 = bfp2f(u1.y), a2 = bfp2f(u1.z), a3 = bfp2f(u1.w);
            acc[0] = fmaf(a0.x, n1, acc[0]); acc[1] = fmaf(a0.y, n1, acc[1]);
            acc[2] = fmaf(a1.x, n1, acc[2]); acc[3] = fmaf(a1.y, n1, acc[3]);
            acc[4] = fmaf(a2.x, n1, acc[4]); acc[5] = fmaf(a2.y, n1, acc[5]);
            acc[6] = fmaf(a3.x, n1, acc[6]); acc[7] = fmaf(a3.y, n1, acc[7]);
        }
        {
            float2 a0 = bfp2f(u2.x), a1 = bfp2f(u2.y), a2 = bfp2f(u2.z), a3 = bfp2f(u2.w);
            acc[0] = fmaf(a0.x, n2, acc[0]); acc[1] = fmaf(a0.y, n2, acc[1]);
            acc[2] = fmaf(a1.x, n2, acc[2]); acc[3] = fmaf(a1.y, n2, acc[3]);
            acc[4] = fmaf(a2.x, n2, acc[4]); acc[5] = fmaf(a2.y, n2, acc[5]);
            acc[6] = fmaf(a3.x, n2, acc[6]); acc[7] = fmaf(a3.y, n2, acc[7]);
        }
        {
            float2 a0 = bfp2f(u3.x), a1 = bfp2f(u3.y), a2 = bfp2f(u3.z), a3 = bfp2f(u3.w);
            acc[0] = fmaf(a0.x, n3, acc[0]); acc[1] = fmaf(a0.y, n3, acc[1]);
            acc[2] = fmaf(a1.x, n3, acc[2]); acc[3] = fmaf(a1.y, n3, acc[3]);
            acc[4] = fmaf(a2.x, n3, acc[4]); acc[5] = fmaf(a2.y, n3, acc[5]);
            acc[6] = fmaf(a3.x, n3, acc[6]); acc[7] = fmaf(a3.y, n3, acc[7]);
        }
    }
    for (; p < end; p += 4) {
        int2 e0 = nt_ld_i2(csr + p);
        float n0 = __int_as_float(e0.y) * dinv[e0.x];
        uint4 u0 = xb[(size_t)e0.x * 16 + l];
        float2 a0 = bfp2f(u0.x), a1 = bfp2f(u0.y), a2 = bfp2f(u0.z), a3 = bfp2f(u0.w);
        acc[0] = fmaf(a0.x, n0, acc[0]); acc[1] = fmaf(a0.y, n0, acc[1]);
        acc[2] = fmaf(a1.x, n0, acc[2]); acc[3] = fmaf(a1.y, n0, acc[3]);
        acc[4] = fmaf(a2.x, n0, acc[4]); acc[5] = fmaf(a2.y, n0, acc[5]);
        acc[6] = fmaf(a3.x, n0, acc[6]); acc[7] = fmaf(a3.y, n0, acc[7]);
    }
#pragma unroll
    for (int j = 0; j < 8; ++j) {
        acc[j] += __shfl_xor(acc[j], 16);
        acc[j] += __shfl_xor(acc[j], 32);
    }
    if (q == 0) {
        uint4 o;
        o.x = packbf(acc[0] * di, acc[1] * di);
        o.y = packbf(acc[2] * di, acc[3] * di);
        o.z = packbf(acc[4] * di, acc[5] * di);
        o.w = packbf(acc[6] * di, acc[7] * di);
        nt_st_u4(axb + (size_t)node * 16 + l, o);
    }
}

// MFMA MLP: hwb = bf16( relu(axb @ W1 + b1) @ Wcat ).  Block = 64 rows, 4 waves.
__global__ __launch_bounds__(256) void k_mfma_mlp(const unsigned short* __restrict__ axb,
                                                  const unsigned short* __restrict__ w1t,
                                                  const unsigned short* __restrict__ wct,
                                                  const float* __restrict__ b1,
                                                  unsigned short* __restrict__ hwb, int N) {
    __shared__ __align__(16) unsigned short hs[4][16][136];  // +8 pad: bank spread
    const int wave = threadIdx.x >> 6;
    const int lane = threadIdx.x & 63;
    const int lrow = lane & 15;
    const int lk = lane >> 4;            // 0..3
    const int R0 = blockIdx.x * 64 + wave * 16;
    const bool active = (R0 < N);        // N%16==0: active waves fully in-bounds

    if (active) {
        f32x4 acc[8];
#pragma unroll
        for (int t = 0; t < 8; ++t) acc[t] = (f32x4){0.f, 0.f, 0.f, 0.f};
        const unsigned short* arow = axb + (size_t)(R0 + lrow) * DIM + lk * 8;
#pragma unroll
        for (int kt = 0; kt < 4; ++kt) {
            bf16x8 a = __builtin_nontemporal_load(
                reinterpret_cast<const bf16x8*>(arow + kt * 32));
#pragma unroll
            for (int t = 0; t < 8; ++t) {
                bf16x8 b = *reinterpret_cast<const bf16x8*>(
                    w1t + (size_t)(t * 16 + lrow) * DIM + kt * 32 + lk * 8);
                acc[t] = __builtin_amdgcn_mfma_f32_16x16x32_bf16(a, b, acc[t], 0, 0, 0);
            }
        }
#pragma unroll
        for (int t = 0; t < 8; ++t) {
#pragma unroll
            for (int r = 0; r < 4; ++r) {
                int col = t * 16 + lrow;
                float v = acc[t][r] + b1[col];
                hs[wave][lk * 4 + r][col] = f2bf(v > 0.f ? v : 0.f);
            }
        }
    }
    __syncthreads();
    if (active) {
        f32x4 acc2[4];
#pragma unroll
        for (int t = 0; t < 4; ++t) acc2[t] = (f32x4){0.f, 0.f, 0.f, 0.f};
        const unsigned short* hrow = &hs[wave][lrow][0];
#pragma unroll
        for (int kt = 0; kt < 4; ++kt) {
            bf16x8 a = *reinterpret_cast<const bf16x8*>(hrow + kt * 32 + lk * 8);
#pragma unroll
            for (int t = 0; t < 4; ++t) {
                bf16x8 b = *reinterpret_cast<const bf16x8*>(
                    wct + (size_t)(t * 16 + lrow) * DIM + kt * 32 + lk * 8);
                acc2[t] = __builtin_amdgcn_mfma_f32_16x16x32_bf16(a, b, acc2[t], 0, 0, 0);
            }
        }
#pragma unroll
        for (int t = 0; t < 4; ++t)
#pragma unroll
            for (int r = 0; r < 4; ++r)
                hwb[(size_t)(R0 + lk * 4 + r) * 64 + t * 16 + lrow] = f2bf(acc2[t][r]);
    }
}

// wave per node; quarter-interleaved edges; 16 lanes x uint2 = 128B row;
// unroll-4 per quarter; shfl_xor(16/32); quarter 0 writes float4 (nt).
__global__ __launch_bounds__(256) void k_gather64(const int2* __restrict__ csr,
                                                  const int* __restrict__ rowptr,
                                                  const float* __restrict__ dinv,
                                                  const uint2* __restrict__ hwb,
                                                  const float* __restrict__ bm,
                                                  const float* __restrict__ bs,
                                                  float* __restrict__ outm,
                                                  float* __restrict__ outs, int N) {
    int node = (blockIdx.x * 256 + threadIdx.x) >> 6;
    int lane = threadIdx.x & 63;
    if (node >= N) return;
    const int q = lane >> 4;
    const int l = lane & 15;          // dims 4l..4l+3
    float di = dinv[node];
    float acc[4];
#pragma unroll
    for (int j = 0; j < 4; ++j) acc[j] = 0.f;
    if (q == 0) {                     // self-loop once
        uint2 sv = hwb[(size_t)node * 16 + l];
        float sl = 2.0f * di;
        float2 s0 = bfp2f(sv.x), s1 = bfp2f(sv.y);
        acc[0] = s0.x * sl; acc[1] = s0.y * sl;
        acc[2] = s1.x * sl; acc[3] = s1.y * sl;
    }
    int p = rowptr[node] + q;
    int end = rowptr[node + 1];
    for (; p + 12 < end; p += 16) {
        int2 e0 = nt_ld_i2(csr + p);
        int2 e1 = nt_ld_i2(csr + p + 4);
        int2 e2 = nt_ld_i2(csr + p + 8);
        int2 e3 = nt_ld_i2(csr + p + 12);
        float n0 = __int_as_float(e0.y) * dinv[e0.x];
        float n1 = __int_as_float(e1.y) * dinv[e1.x];
        float n2 = __int_as_float(e2.y) * dinv[e2.x];
        float n3 = __int_as_float(e3.y) * dinv[e3.x];
        uint2 u0 = hwb[(size_t)e0.x * 16 + l];
        uint2 u1 = hwb[(size_t)e1.x * 16 + l];
        uint2 u2 = hwb[(size_t)e2.x * 16 + l];
        uint2 u3 = hwb[(size_t)e3.x * 16 + l];
        float2 a0 = bfp2f(u0.x), a1 = bfp2f(u0.y);
        acc[0] = fmaf(a0.x, n0, acc[0]); acc[1] = fmaf(a0.y, n0, acc[1]);
        acc[2] = fmaf(a1.x, n0, acc[2]); acc[3] = fmaf(a1.y, n0, acc[3]);
        float2 b0 = bfp2f(u1.x), b1 = bfp2f(u1.y);
        acc[0] = fmaf(b0.x, n1, acc[0]); acc[1] = fmaf(b0.y, n1, acc[1]);
        acc[2] = fmaf(b1.x, n1, acc[2]); acc[3] = fmaf(b1.y, n1, acc[3]);
        float2 c0 = bfp2f(u2.x), c1 = bfp2f(u2.y);
        acc[0] = fmaf(c0.x, n2, acc[0]); acc[1] = fmaf(c0.y, n2, acc[1]);
        acc[2] = fmaf(c1.x, n2, acc[2]); acc[3] = fmaf(c1.y, n2, acc[3]);
        float2 d0 = bfp2f(u3.x), d1 = bfp2f(u3.y);
        acc[0] = fmaf(d0.x, n3, acc[0]); acc[1] = fmaf(d0.y, n3, acc[1]);
        acc[2] = fmaf(d1.x, n3, acc[2]); acc[3] = fmaf(d1.y, n3, acc[3]);
    }
    for (; p < end; p += 4) {
        int2 e0 = nt_ld_i2(csr + p);
        float n0 = __int_as_float(e0.y) * dinv[e0.x];
        uint2 u0 = hwb[(size_t)e0.x * 16 + l];
        float2 a0 = bfp2f(u0.x), a1 = bfp2f(u0.y);
        acc[0] = fmaf(a0.x, n0, acc[0]); acc[1] = fmaf(a0.y, n0, acc[1]);
        acc[2] = fmaf(a1.x, n0, acc[2]); acc[3] = fmaf(a1.y, n0, acc[3]);
    }
#pragma unroll
    for (int j = 0; j < 4; ++j) {
        acc[j] += __shfl_xor(acc[j], 16);
        acc[j] += __shfl_xor(acc[j], 32);
    }
    if (q == 0) {
        if (l < 8) {
            float4 bb = reinterpret_cast<const float4*>(bm)[l];
            float4 val;
            val.x = acc[0] * di + bb.x;
            val.y = acc[1] * di + bb.y;
            val.z = acc[2] * di + bb.z;
            val.w = acc[3] * di + bb.w;
            nt_st_f4(reinterpret_cast<float4*>(outm + (size_t)node * LAT) + l, val);
        } else {
            float4 bb = reinterpret_cast<const float4*>(bs)[l - 8];
            float4 val;
            val.x = acc[0] * di + bb.x;
            val.y = acc[1] * di + bb.y;
            val.z = acc[2] * di + bb.z;
            val.w = acc[3] * di + bb.w;
            nt_st_f4(reinterpret_cast<float4*>(outs + (size_t)node * LAT) + l - 8, val);
        }
    }
}

extern "C" void kernel_launch(void* const* d_in, const int* in_sizes, int n_in,
                              void* d_out, int out_size, void* d_ws, size_t ws_size,
                              hipStream_t stream) {
    const float* x  = (const float*)d_in[0];
    const int*   ei = (const int*)d_in[1];
    const float* ew = (const float*)d_in[2];
    const float* W1 = (const float*)d_in[3];
    const float* b1 = (const float*)d_in[4];
    const float* Wm = (const float*)d_in[5];
    const float* bm = (const float*)d_in[6];
    const float* Ws = (const float*)d_in[7];
    const float* bs = (const float*)d_in[8];

    const int N = in_sizes[0] / DIM;     // 100000
    const int E = in_sizes[1] / 2;       // 1600000
    const int* src = ei;
    const int* dst = ei + E;

    const int NCH = (E + CHUNK - 1) / CHUNK;   // 391 chunks
    const int NBK = (N + 255) >> BSH;          // 391 buckets

    // ---- workspace layout (~91 MB) ----
    char* w = (char*)d_ws;
    unsigned* xb  = (unsigned*)w;            w += (size_t)N * DIM * 2;       // 25.6 MB bf16 x
    unsigned* axb = (unsigned*)w;            w += (size_t)N * DIM * 2;       // 25.6 MB bf16 ax
    unsigned short* hwb = (unsigned short*)w; w += (size_t)N * 64 * 2;       // 12.8 MB bf16 hw
    float* dinv = (float*)w;                 w += (size_t)N * 4;
    int*   rowptr = (int*)w;                 w += (size_t)(N + 1) * 4;
    w = (char*)(((size_t)w + 255) & ~(size_t)255);
    int*   gh    = (int*)w;                  w += (size_t)NBK * NCH * 4;     // 612 KB
    int*   btot  = (int*)w;                  w += (size_t)NBK * 4;
    int*   bbase = (int*)w;                  w += (size_t)(NBK + 1) * 4;
    w = (char*)(((size_t)w + 255) & ~(size_t)255);
    unsigned short* w1t = (unsigned short*)w; w += DIM * DIM * 2;            // 32 KB
    unsigned short* wct = (unsigned short*)w; w += 64 * DIM * 2;             // 16 KB
    w = (char*)(((size_t)w + 255) & ~(size_t)255);
    int2*  bkt   = (int2*)w;                 w += (size_t)E * 8;             // 12.8 MB
    w = (char*)(((size_t)w + 255) & ~(size_t)255);
    int2*  csr   = (int2*)w;                 // 12.8 MB

    float* outm = (float*)d_out;
    float* outs = outm + (size_t)N * LAT;

    const int B = 256;
    const int XB = (N * DIM / 16) / 256;                // 3125 x2bf blocks
    const int WB = (DIM * DIM + 64 * DIM) / 256;        // 96 weight blocks

    // 1. chunk histograms + x->bf16 + weight prep (fused)
    k_hist<<<NCH + XB + WB, B, 0, stream>>>(dst, E, gh, NCH, NBK, x, (uint4*)xb,
                                            W1, Wm, Ws, w1t, wct, XB);
    // 2. bucket totals; scan gh in place to global positions
    k_btot<<<NBK, B, 0, stream>>>(gh, NCH, btot);
    k_rowscan<<<NBK, B, 0, stream>>>(gh, NCH, NBK, btot, bbase, E);
    // 3. scatter edges to bucket order (LDS cursors)
    k_bucket<<<NCH, B, 0, stream>>>(src, dst, ew, gh, NCH, NBK, bkt, E);
    // 4. per-bucket exact placement: rowptr, csr, dinv
    k_build<<<NBK, B, 0, stream>>>(bkt, bbase, rowptr, csr, dinv, N, E);

    // 5. ax = Agg(xb) -> bf16
    k_gather128<<<(N + 3) / 4, B, 0, stream>>>(csr, rowptr, dinv, (const uint4*)xb, (uint4*)axb, N);
    // 6. hwb = bf16( relu(ax@W1+b1) @ [Wm|Ws] )  (MFMA)
    k_mfma_mlp<<<(N + 63) / 64, B, 0, stream>>>((const unsigned short*)axb, w1t, wct, b1, hwb, N);
    // 7. z = Agg(hwb) + bias -> outputs
    k_gather64<<<(N + 3) / 4, B, 0, stream>>>(csr, rowptr, dinv, (const uint2*)hwb, bm, bs, outm, outs, N);
}

// Round 15
// 254.689 us; speedup vs baseline: 1.2162x; 1.2162x over previous
//
#include <hip/hip_runtime.h>

// VGAE encoder: 3x GCNConv (improved=True), N=100000, E=1600000.
//   xb = bf16(x); ax = Agg(xb); hw = relu(ax@W1+b1)@[Wm|Ws] (MFMA); z = Agg(hw)+[bm|bs]
// R15: exact revert to R12 (best: 255.7us). R13/R14 falsified the L2-pollution
// theory: nontemporal hints on csr/outputs REGRESSED gathers 1.7x (nt demotes
// the load path; csr loads sit on the gather's address-dependence chain).
// Gathers are at the random-access concurrency floor (R8-R10: stream count
// saturated at ~8-16 streams/wave; R13/R14: cache policy neutral-to-negative).

#define DIM 128
#define LAT 32
#define CHUNK 4096        // edges per histogram/scatter block
#define BSH 8             // bucket shift: bucket = dst>>8 (256 nodes/bucket)

typedef short bf16x8 __attribute__((ext_vector_type(8)));
typedef float f32x4 __attribute__((ext_vector_type(4)));

__device__ __forceinline__ unsigned short f2bf(float f) {   // RNE
    unsigned u = __float_as_uint(f);
    return (unsigned short)((u + 0x7fffu + ((u >> 16) & 1u)) >> 16);
}
__device__ __forceinline__ unsigned packbf(float a, float b) {
    return (unsigned)f2bf(a) | ((unsigned)f2bf(b) << 16);
}
__device__ __forceinline__ float2 bfp2f(unsigned u) {
    float2 r;
    r.x = __uint_as_float(u << 16);
    r.y = __uint_as_float(u & 0xffff0000u);
    return r;
}

// FUSED: blocks [0,NCH): per-chunk bucket histogram -> gh[bin*NCH+chunk];
// [NCH,NCH+XB): x f32->bf16; rest: weight transpose+cast.
__global__ __launch_bounds__(256) void k_hist(const int* __restrict__ dst, int E,
                                              int* __restrict__ gh, int NCH, int NBK,
                                              const float* __restrict__ x,
                                              uint4* __restrict__ xb,
                                              const float* __restrict__ W1,
                                              const float* __restrict__ Wm,
                                              const float* __restrict__ Ws,
                                              unsigned short* __restrict__ w1t,
                                              unsigned short* __restrict__ wct,
                                              int XB) {
    const int c = blockIdx.x;
    if (c < NCH) {
        __shared__ int h[512];
        for (int b = threadIdx.x; b < NBK; b += 256) h[b] = 0;
        __syncthreads();
        int end = min(E, (c + 1) * CHUNK);
        for (int e = c * CHUNK + threadIdx.x; e < end; e += 256)
            atomicAdd(&h[dst[e] >> BSH], 1);
        __syncthreads();
        for (int b = threadIdx.x; b < NBK; b += 256) gh[b * NCH + c] = h[b];
    } else if (c < NCH + XB) {
        size_t i = ((size_t)(c - NCH) * 256 + threadIdx.x) * 16;
        const float4* xin = reinterpret_cast<const float4*>(x + i);
        float4 v0 = xin[0], v1 = xin[1], v2 = xin[2], v3 = xin[3];
        uint4 o0, o1;
        o0.x = packbf(v0.x, v0.y); o0.y = packbf(v0.z, v0.w);
        o0.z = packbf(v1.x, v1.y); o0.w = packbf(v1.z, v1.w);
        o1.x = packbf(v2.x, v2.y); o1.y = packbf(v2.z, v2.w);
        o1.z = packbf(v3.x, v3.y); o1.w = packbf(v3.z, v3.w);
        xb[i / 8] = o0;
        xb[i / 8 + 1] = o1;
    } else {
        int i = (c - NCH - XB) * 256 + threadIdx.x;
        if (i < DIM * DIM) {
            int cc = i >> 7, k = i & 127;
            w1t[cc * DIM + k] = f2bf(W1[k * DIM + cc]);
        }
        i -= DIM * DIM;
        if (i >= 0 && i < 64 * DIM) {
            int cc = i >> 7, k = i & 127;
            wct[cc * DIM + k] = f2bf((cc < LAT) ? Wm[k * LAT + cc] : Ws[k * LAT + (cc - LAT)]);
        }
    }
}

// per-bucket total: btot[b] = sum over chunks of gh[b][*]
__global__ __launch_bounds__(256) void k_btot(const int* __restrict__ gh, int NCH,
                                              int* __restrict__ btot) {
    __shared__ int sdata[256];
    const int b = blockIdx.x;
    int sum = 0;
    for (int t = threadIdx.x; t < NCH; t += 256) sum += gh[b * NCH + t];
    sdata[threadIdx.x] = sum;
    __syncthreads();
    for (int off = 128; off > 0; off >>= 1) {
        if (threadIdx.x < off) sdata[threadIdx.x] += sdata[threadIdx.x + off];
        __syncthreads();
    }
    if (threadIdx.x == 0) btot[b] = sdata[0];
}

// per-bucket row scan: gh[b][c] -> bbase[b] + exclusive prefix (global positions).
__global__ __launch_bounds__(256) void k_rowscan(int* __restrict__ gh, int NCH, int NBK,
                                                 const int* __restrict__ btot,
                                                 int* __restrict__ bbase, int E) {
    __shared__ int sdata[256];
    __shared__ int basepfx;
    const int b = blockIdx.x;
    const int t = threadIdx.x;
    if (t == 0) {
        int s = 0;
        for (int j = 0; j < b; ++j) s += btot[j];
        basepfx = s;
        bbase[b] = s;
        if (b == NBK - 1) bbase[NBK] = s + btot[b];
    }
    __syncthreads();
    int i0 = 2 * t, i1 = 2 * t + 1;
    int v0 = (i0 < NCH) ? gh[b * NCH + i0] : 0;
    int v1 = (i1 < NCH) ? gh[b * NCH + i1] : 0;
    int tot = v0 + v1;
    sdata[t] = tot;
    __syncthreads();
    for (int off = 1; off < 256; off <<= 1) {
        int xv = 0;
        if (t >= off) xv = sdata[t - off];
        __syncthreads();
        if (t >= off) sdata[t] += xv;
        __syncthreads();
    }
    int pfx = basepfx + sdata[t] - tot;   // exclusive across pairs
    if (i0 < NCH) gh[b * NCH + i0] = pfx;
    if (i1 < NCH) gh[b * NCH + i1] = pfx + v0;
}

// scatter edges into bucket-ordered bkt[]: LDS cursors, NO global atomics.
// record = {src | (dst&255)<<17, ew bits}
__global__ __launch_bounds__(256) void k_bucket(const int* __restrict__ src,
                                                const int* __restrict__ dst,
                                                const float* __restrict__ ew,
                                                const int* __restrict__ gh, int NCH, int NBK,
                                                int2* __restrict__ bkt, int E) {
    __shared__ int cur[512];
    const int c = blockIdx.x;
    for (int b = threadIdx.x; b < NBK; b += 256) cur[b] = gh[b * NCH + c];
    __syncthreads();
    int end = min(E, (c + 1) * CHUNK);
    for (int e = c * CHUNK + threadIdx.x; e < end; e += 256) {
        int d = dst[e];
        int b = d >> BSH;
        int p = atomicAdd(&cur[b], 1);    // LDS atomic: fast
        bkt[p] = make_int2(src[e] | ((d & 255) << 17), __float_as_int(ew[e]));
    }
}

// per-bucket exact placement: rowptr + csr + deg/dinv, all LDS-local.
__global__ __launch_bounds__(256) void k_build(const int2* __restrict__ bkt,
                                               const int* __restrict__ bbase,
                                               int* __restrict__ rowptr,
                                               int2* __restrict__ csr,
                                               float* __restrict__ dinv, int N, int E) {
    __shared__ int cnt[256];
    __shared__ int offs[256];
    __shared__ int cnt2[256];
    __shared__ float degf[256];
    __shared__ int sdata[256];
    const int b = blockIdx.x;
    const int t = threadIdx.x;
    const int start = bbase[b], endb = bbase[b + 1];
    cnt[t] = 0; cnt2[t] = 0; degf[t] = 0.f;
    __syncthreads();
    for (int idx = start + t; idx < endb; idx += 256) {
        int2 rec = bkt[idx];
        int dl = (rec.x >> 17) & 255;
        atomicAdd(&cnt[dl], 1);
        atomicAdd(&degf[dl], __int_as_float(rec.y));
    }
    __syncthreads();
    int myc = cnt[t];
    sdata[t] = myc;
    __syncthreads();
    for (int off = 1; off < 256; off <<= 1) {
        int xv = 0;
        if (t >= off) xv = sdata[t - off];
        __syncthreads();
        if (t >= off) sdata[t] += xv;
        __syncthreads();
    }
    offs[t] = sdata[t] - myc;             // exclusive
    int node = (b << BSH) + t;
    if (node < N) {
        rowptr[node] = start + offs[t];
        float deg = 2.0f + degf[t];       // improved=True self-loop weight
        dinv[node] = (deg > 0.0f) ? rsqrtf(deg) : 0.0f;
    }
    if (b == 0 && t == 0) rowptr[N] = E;
    __syncthreads();
    for (int idx = start + t; idx < endb; idx += 256) {
        int2 rec = bkt[idx];
        int dl = (rec.x >> 17) & 255;
        int r = atomicAdd(&cnt2[dl], 1);
        csr[start + offs[dl] + r] = make_int2(rec.x & 0x1FFFF, rec.y);
    }
}

// wave per node; quarter q handles edges p0+q, p0+q+4,...; 16 lanes x uint4 = 256B row;
// unroll-4 per quarter; shfl_xor(16/32) combine; quarter 0 writes.
// Deferred norm: ax = di*(2*di*x[d] + sum ew*dinv[s]*x[s]).
__global__ __launch_bounds__(256) void k_gather128(const int2* __restrict__ csr,
                                                   const int* __restrict__ rowptr,
                                                   const float* __restrict__ dinv,
                                                   const uint4* __restrict__ xb,
                                                   uint4* __restrict__ axb, int N) {
    int node = (blockIdx.x * 256 + threadIdx.x) >> 6;
    int lane = threadIdx.x & 63;
    if (node >= N) return;
    const int q = lane >> 4;
    const int l = lane & 15;
    float di = dinv[node];
    float acc[8];
#pragma unroll
    for (int j = 0; j < 8; ++j) acc[j] = 0.f;
    if (q == 0) {                  // self-loop once
        uint4 sv = xb[(size_t)node * 16 + l];
        float sl = 2.0f * di;
        float2 s0 = bfp2f(sv.x), s1 = bfp2f(sv.y), s2 = bfp2f(sv.z), s3 = bfp2f(sv.w);
        acc[0] = s0.x * sl; acc[1] = s0.y * sl;
        acc[2] = s1.x * sl; acc[3] = s1.y * sl;
        acc[4] = s2.x * sl; acc[5] = s2.y * sl;
        acc[6] = s3.x * sl; acc[7] = s3.y * sl;
    }
    int p = rowptr[node] + q;
    int end = rowptr[node + 1];
    for (; p + 12 < end; p += 16) {     // unroll-4 within quarter (stride 4)
        int2 e0 = csr[p], e1 = csr[p + 4], e2 = csr[p + 8], e3 = csr[p + 12];
        float n0 = __int_as_float(e0.y) * dinv[e0.x];
        float n1 = __int_as_float(e1.y) * dinv[e1.x];
        float n2 = __int_as_float(e2.y) * dinv[e2.x];
        float n3 = __int_as_float(e3.y) * dinv[e3.x];
        uint4 u0 = xb[(size_t)e0.x * 16 + l];
        uint4 u1 = xb[(size_t)e1.x * 16 + l];
        uint4 u2 = xb[(size_t)e2.x * 16 + l];
        uint4 u3 = xb[(size_t)e3.x * 16 + l];
        {
            float2 a0 = bfp2f(u0.x), a1 = bfp2f(u0.y), a2 = bfp2f(u0.z), a3 = bfp2f(u0.w);
            acc[0] = fmaf(a0.x, n0, acc[0]); acc[1] = fmaf(a0.y, n0, acc[1]);
            acc[2] = fmaf(a1.x, n0, acc[2]); acc[3] = fmaf(a1.y, n0, acc[3]);
            acc[4] = fmaf(a2.x, n0, acc[4]); acc[5] = fmaf(a2.y, n0, acc[5]);
            acc[6] = fmaf(a3.x, n0, acc[6]); acc[7] = fmaf(a3.y, n0, acc[7]);
        }
        {
            float2 a0 = bfp2f(u1.x), a1 = bfp2f(u1.y), a2 = bfp2f(u1.z), a3 = bfp2f(u1.w);
            acc[0] = fmaf(a0.x, n1, acc[0]); acc[1] = fmaf(a0.y, n1, acc[1]);
            acc[2] = fmaf(a1.x, n1, acc[2]); acc[3] = fmaf(a1.y, n1, acc[3]);
            acc[4] = fmaf(a2.x, n1, acc[4]); acc[5] = fmaf(a2.y, n1, acc[5]);
            acc[6] = fmaf(a3.x, n1, acc[6]); acc[7] = fmaf(a3.y, n1, acc[7]);
        }
        {
            float2 a0 = bfp2f(u2.x), a1 = bfp2f(u2.y), a2 = bfp2f(u2.z), a3 = bfp2f(u2.w);
            acc[0] = fmaf(a0.x, n2, acc[0]); acc[1] = fmaf(a0.y, n2, acc[1]);
            acc[2] = fmaf(a1.x, n2, acc[2]); acc[3] = fmaf(a1.y, n2, acc[3]);
            acc[4] = fmaf(a2.x, n2, acc[4]); acc[5] = fmaf(a2.y, n2, acc[5]);
            acc[6] = fmaf(a3.x, n2, acc[6]); acc[7] = fmaf(a3.y, n2, acc[7]);
        }
        {
            float2 a0 = bfp2f(u3.x), a1 = bfp2f(u3.y), a2 = bfp2f(u3.z), a3 = bfp2f(u3.w);
            acc[0] = fmaf(a0.x, n3, acc[0]); acc[1] = fmaf(a0.y, n3, acc[1]);
            acc[2] = fmaf(a1.x, n3, acc[2]); acc[3] = fmaf(a1.y, n3, acc[3]);
            acc[4] = fmaf(a2.x, n3, acc[4]); acc[5] = fmaf(a2.y, n3, acc[5]);
            acc[6] = fmaf(a3.x, n3, acc[6]); acc[7] = fmaf(a3.y, n3, acc[7]);
        }
    }
    for (; p < end; p += 4) {
        int2 e0 = csr[p];
        float n0 = __int_as_float(e0.y) * dinv[e0.x];
        uint4 u0 = xb[(size_t)e0.x * 16 + l];
        float2 a0 = bfp2f(u0.x), a1 = bfp2f(u0.y), a2 = bfp2f(u0.z), a3 = bfp2f(u0.w);
        acc[0] = fmaf(a0.x, n0, acc[0]); acc[1] = fmaf(a0.y, n0, acc[1]);
        acc[2] = fmaf(a1.x, n0, acc[2]); acc[3] = fmaf(a1.y, n0, acc[3]);
        acc[4] = fmaf(a2.x, n0, acc[4]); acc[5] = fmaf(a2.y, n0, acc[5]);
        acc[6] = fmaf(a3.x, n0, acc[6]); acc[7] = fmaf(a3.y, n0, acc[7]);
    }
#pragma unroll
    for (int j = 0; j < 8; ++j) {
        acc[j] += __shfl_xor(acc[j], 16);
        acc[j] += __shfl_xor(acc[j], 32);
    }
    if (q == 0) {
        uint4 o;
        o.x = packbf(acc[0] * di, acc[1] * di);
        o.y = packbf(acc[2] * di, acc[3] * di);
        o.z = packbf(acc[4] * di, acc[5] * di);
        o.w = packbf(acc[6] * di, acc[7] * di);
        axb[(size_t)node * 16 + l] = o;
    }
}

// MFMA MLP: hwb = bf16( relu(axb @ W1 + b1) @ Wcat ).  Block = 64 rows, 4 waves.
__global__ __launch_bounds__(256) void k_mfma_mlp(const unsigned short* __restrict__ axb,
                                                  const unsigned short* __restrict__ w1t,
                                                  const unsigned short* __restrict__ wct,
                                                  const float* __restrict__ b1,
                                                  unsigned short* __restrict__ hwb, int N) {
    __shared__ __align__(16) unsigned short hs[4][16][136];  // +8 pad: bank spread
    const int wave = threadIdx.x >> 6;
    const int lane = threadIdx.x & 63;
    const int lrow = lane & 15;
    const int lk = lane >> 4;            // 0..3
    const int R0 = blockIdx.x * 64 + wave * 16;
    const bool active = (R0 < N);        // N%16==0: active waves fully in-bounds

    if (active) {
        f32x4 acc[8];
#pragma unroll
        for (int t = 0; t < 8; ++t) acc[t] = (f32x4){0.f, 0.f, 0.f, 0.f};
        const unsigned short* arow = axb + (size_t)(R0 + lrow) * DIM + lk * 8;
#pragma unroll
        for (int kt = 0; kt < 4; ++kt) {
            bf16x8 a = *reinterpret_cast<const bf16x8*>(arow + kt * 32);
#pragma unroll
            for (int t = 0; t < 8; ++t) {
                bf16x8 b = *reinterpret_cast<const bf16x8*>(
                    w1t + (size_t)(t * 16 + lrow) * DIM + kt * 32 + lk * 8);
                acc[t] = __builtin_amdgcn_mfma_f32_16x16x32_bf16(a, b, acc[t], 0, 0, 0);
            }
        }
#pragma unroll
        for (int t = 0; t < 8; ++t) {
#pragma unroll
            for (int r = 0; r < 4; ++r) {
                int col = t * 16 + lrow;
                float v = acc[t][r] + b1[col];
                hs[wave][lk * 4 + r][col] = f2bf(v > 0.f ? v : 0.f);
            }
        }
    }
    __syncthreads();
    if (active) {
        f32x4 acc2[4];
#pragma unroll
        for (int t = 0; t < 4; ++t) acc2[t] = (f32x4){0.f, 0.f, 0.f, 0.f};
        const unsigned short* hrow = &hs[wave][lrow][0];
#pragma unroll
        for (int kt = 0; kt < 4; ++kt) {
            bf16x8 a = *reinterpret_cast<const bf16x8*>(hrow + kt * 32 + lk * 8);
#pragma unroll
            for (int t = 0; t < 4; ++t) {
                bf16x8 b = *reinterpret_cast<const bf16x8*>(
                    wct + (size_t)(t * 16 + lrow) * DIM + kt * 32 + lk * 8);
                acc2[t] = __builtin_amdgcn_mfma_f32_16x16x32_bf16(a, b, acc2[t], 0, 0, 0);
            }
        }
#pragma unroll
        for (int t = 0; t < 4; ++t)
#pragma unroll
            for (int r = 0; r < 4; ++r)
                hwb[(size_t)(R0 + lk * 4 + r) * 64 + t * 16 + lrow] = f2bf(acc2[t][r]);
    }
}

// wave per node; quarter-interleaved edges; 16 lanes x uint2 = 128B row;
// unroll-4 per quarter; shfl_xor(16/32); quarter 0 writes float4.
__global__ __launch_bounds__(256) void k_gather64(const int2* __restrict__ csr,
                                                  const int* __restrict__ rowptr,
                                                  const float* __restrict__ dinv,
                                                  const uint2* __restrict__ hwb,
                                                  const float* __restrict__ bm,
                                                  const float* __restrict__ bs,
                                                  float* __restrict__ outm,
                                                  float* __restrict__ outs, int N) {
    int node = (blockIdx.x * 256 + threadIdx.x) >> 6;
    int lane = threadIdx.x & 63;
    if (node >= N) return;
    const int q = lane >> 4;
    const int l = lane & 15;          // dims 4l..4l+3
    float di = dinv[node];
    float acc[4];
#pragma unroll
    for (int j = 0; j < 4; ++j) acc[j] = 0.f;
    if (q == 0) {                     // self-loop once
        uint2 sv = hwb[(size_t)node * 16 + l];
        float sl = 2.0f * di;
        float2 s0 = bfp2f(sv.x), s1 = bfp2f(sv.y);
        acc[0] = s0.x * sl; acc[1] = s0.y * sl;
        acc[2] = s1.x * sl; acc[3] = s1.y * sl;
    }
    int p = rowptr[node] + q;
    int end = rowptr[node + 1];
    for (; p + 12 < end; p += 16) {
        int2 e0 = csr[p], e1 = csr[p + 4], e2 = csr[p + 8], e3 = csr[p + 12];
        float n0 = __int_as_float(e0.y) * dinv[e0.x];
        float n1 = __int_as_float(e1.y) * dinv[e1.x];
        float n2 = __int_as_float(e2.y) * dinv[e2.x];
        float n3 = __int_as_float(e3.y) * dinv[e3.x];
        uint2 u0 = hwb[(size_t)e0.x * 16 + l];
        uint2 u1 = hwb[(size_t)e1.x * 16 + l];
        uint2 u2 = hwb[(size_t)e2.x * 16 + l];
        uint2 u3 = hwb[(size_t)e3.x * 16 + l];
        float2 a0 = bfp2f(u0.x), a1 = bfp2f(u0.y);
        acc[0] = fmaf(a0.x, n0, acc[0]); acc[1] = fmaf(a0.y, n0, acc[1]);
        acc[2] = fmaf(a1.x, n0, acc[2]); acc[3] = fmaf(a1.y, n0, acc[3]);
        float2 b0 = bfp2f(u1.x), b1 = bfp2f(u1.y);
        acc[0] = fmaf(b0.x, n1, acc[0]); acc[1] = fmaf(b0.y, n1, acc[1]);
        acc[2] = fmaf(b1.x, n1, acc[2]); acc[3] = fmaf(b1.y, n1, acc[3]);
        float2 c0 = bfp2f(u2.x), c1 = bfp2f(u2.y);
        acc[0] = fmaf(c0.x, n2, acc[0]); acc[1] = fmaf(c0.y, n2, acc[1]);
        acc[2] = fmaf(c1.x, n2, acc[2]); acc[3] = fmaf(c1.y, n2, acc[3]);
        float2 d0 = bfp2f(u3.x), d1 = bfp2f(u3.y);
        acc[0] = fmaf(d0.x, n3, acc[0]); acc[1] = fmaf(d0.y, n3, acc[1]);
        acc[2] = fmaf(d1.x, n3, acc[2]); acc[3] = fmaf(d1.y, n3, acc[3]);
    }
    for (; p < end; p += 4) {
        int2 e0 = csr[p];
        float n0 = __int_as_float(e0.y) * dinv[e0.x];
        uint2 u0 = hwb[(size_t)e0.x * 16 + l];
        float2 a0 = bfp2f(u0.x), a1 = bfp2f(u0.y);
        acc[0] = fmaf(a0.x, n0, acc[0]); acc[1] = fmaf(a0.y, n0, acc[1]);
        acc[2] = fmaf(a1.x, n0, acc[2]); acc[3] = fmaf(a1.y, n0, acc[3]);
    }
#pragma unroll
    for (int j = 0; j < 4; ++j) {
        acc[j] += __shfl_xor(acc[j], 16);
        acc[j] += __shfl_xor(acc[j], 32);
    }
    if (q == 0) {
        if (l < 8) {
            float4 bb = reinterpret_cast<const float4*>(bm)[l];
            float4 val;
            val.x = acc[0] * di + bb.x;
            val.y = acc[1] * di + bb.y;
            val.z = acc[2] * di + bb.z;
            val.w = acc[3] * di + bb.w;
            reinterpret_cast<float4*>(outm + (size_t)node * LAT)[l] = val;
        } else {
            float4 bb = reinterpret_cast<const float4*>(bs)[l - 8];
            float4 val;
            val.x = acc[0] * di + bb.x;
            val.y = acc[1] * di + bb.y;
            val.z = acc[2] * di + bb.z;
            val.w = acc[3] * di + bb.w;
            reinterpret_cast<float4*>(outs + (size_t)node * LAT)[l - 8] = val;
        }
    }
}

extern "C" void kernel_launch(void* const* d_in, const int* in_sizes, int n_in,
                              void* d_out, int out_size, void* d_ws, size_t ws_size,
                              hipStream_t stream) {
    const float* x  = (const float*)d_in[0];
    const int*   ei = (const int*)d_in[1];
    const float* ew = (const float*)d_in[2];
    const float* W1 = (const float*)d_in[3];
    const float* b1 = (const float*)d_in[4];
    const float* Wm = (const float*)d_in[5];
    const float* bm = (const float*)d_in[6];
    const float* Ws = (const float*)d_in[7];
    const float* bs = (const float*)d_in[8];

    const int N = in_sizes[0] / DIM;     // 100000
    const int E = in_sizes[1] / 2;       // 1600000
    const int* src = ei;
    const int* dst = ei + E;

    const int NCH = (E + CHUNK - 1) / CHUNK;   // 391 chunks
    const int NBK = (N + 255) >> BSH;          // 391 buckets

    // ---- workspace layout (~91 MB) ----
    char* w = (char*)d_ws;
    unsigned* xb  = (unsigned*)w;            w += (size_t)N * DIM * 2;       // 25.6 MB bf16 x
    unsigned* axb = (unsigned*)w;            w += (size_t)N * DIM * 2;       // 25.6 MB bf16 ax
    unsigned short* hwb = (unsigned short*)w; w += (size_t)N * 64 * 2;       // 12.8 MB bf16 hw
    float* dinv = (float*)w;                 w += (size_t)N * 4;
    int*   rowptr = (int*)w;                 w += (size_t)(N + 1) * 4;
    w = (char*)(((size_t)w + 255) & ~(size_t)255);
    int*   gh    = (int*)w;                  w += (size_t)NBK * NCH * 4;     // 612 KB
    int*   btot  = (int*)w;                  w += (size_t)NBK * 4;
    int*   bbase = (int*)w;                  w += (size_t)(NBK + 1) * 4;
    w = (char*)(((size_t)w + 255) & ~(size_t)255);
    unsigned short* w1t = (unsigned short*)w; w += DIM * DIM * 2;            // 32 KB
    unsigned short* wct = (unsigned short*)w; w += 64 * DIM * 2;             // 16 KB
    w = (char*)(((size_t)w + 255) & ~(size_t)255);
    int2*  bkt   = (int2*)w;                 w += (size_t)E * 8;             // 12.8 MB
    w = (char*)(((size_t)w + 255) & ~(size_t)255);
    int2*  csr   = (int2*)w;                 // 12.8 MB

    float* outm = (float*)d_out;
    float* outs = outm + (size_t)N * LAT;

    const int B = 256;
    const int XB = (N * DIM / 16) / 256;                // 3125 x2bf blocks
    const int WB = (DIM * DIM + 64 * DIM) / 256;        // 96 weight blocks

    // 1. chunk histograms + x->bf16 + weight prep (fused, no atomics to global)
    k_hist<<<NCH + XB + WB, B, 0, stream>>>(dst, E, gh, NCH, NBK, x, (uint4*)xb,
                                            W1, Wm, Ws, w1t, wct, XB);
    // 2. bucket totals; scan gh in place to global positions
    k_btot<<<NBK, B, 0, stream>>>(gh, NCH, btot);
    k_rowscan<<<NBK, B, 0, stream>>>(gh, NCH, NBK, btot, bbase, E);
    // 3. scatter edges to bucket order (LDS cursors)
    k_bucket<<<NCH, B, 0, stream>>>(src, dst, ew, gh, NCH, NBK, bkt, E);
    // 4. per-bucket exact placement: rowptr, csr, dinv
    k_build<<<NBK, B, 0, stream>>>(bkt, bbase, rowptr, csr, dinv, N, E);

    // 5. ax = Agg(xb) -> bf16
    k_gather128<<<(N + 3) / 4, B, 0, stream>>>(csr, rowptr, dinv, (const uint4*)xb, (uint4*)axb, N);
    // 6. hwb = bf16( relu(ax@W1+b1) @ [Wm|Ws] )  (MFMA)
    k_mfma_mlp<<<(N + 63) / 64, B, 0, stream>>>((const unsigned short*)axb, w1t, wct, b1, hwb, N);
    // 7. z = Agg(hwb) + bias -> outputs
    k_gather64<<<(N + 3) / 4, B, 0, stream>>>(csr, rowptr, dinv, (const uint2*)hwb, bm, bs, outm, outs, N);
}